// Round 4
// baseline (1589.951 us; speedup 1.0000x reference)
//
#include <hip/hip_runtime.h>
#include <hip/hip_bf16.h>

// Problem constants (from reference)
#define NN   100000   // nodes
#define NE   600000   // edges
#define INC  128      // in channels
#define HC   128      // heads*per_head = 2*64
#define NH   2        // heads
#define TDIM 64       // time enc dim
#define MSGD 64       // msg dim
#define EDD  128      // edge_attr dim = TDIM + MSGD

#define MPT  128        // rows (edges/nodes) per tile
#define LDK  (EDD + 8)  // padded row (bf16) — 272 B: 16B-aligned rows, 2-way banks only

typedef __hip_bfloat16 bf16;
typedef __attribute__((ext_vector_type(8))) short short8;
typedef __attribute__((ext_vector_type(4))) float floatx4;

static __device__ __forceinline__ float b2f(bf16 h) { return __bfloat162float(h); }
static __device__ __forceinline__ bf16  f2b(float f) { return __float2bfloat16(f); }
static __device__ __forceinline__ float2 bload2(const bf16* p) {
    __hip_bfloat162 h = *reinterpret_cast<const __hip_bfloat162*>(p);
    return __bfloat1622float2(h);
}
// total-order int encoding of float for atomicMax
static __device__ __forceinline__ int   f2ord(float f) { int i = __float_as_int(f); return i >= 0 ? i : i ^ 0x7fffffff; }
static __device__ __forceinline__ float ord2f(int i)   { return __int_as_float(i >= 0 ? i : i ^ 0x7fffffff); }

// ---------------------------------------------------------------------------
// K0: init amax (-inf encoded) and denom (0)
// ---------------------------------------------------------------------------
__global__ __launch_bounds__(256) void k0_init(int* __restrict__ amax, float* __restrict__ denom)
{
    int tid = blockIdx.x * 256 + threadIdx.x;
    if (tid < NN * NH) { amax[tid] = f2ord(-1e30f); denom[tid] = 0.0f; }
}

// ---------------------------------------------------------------------------
// K0b: transpose + bf16-convert the 5 weight matrices: wT[mat][n][k] = W[mat][k][n]
// ---------------------------------------------------------------------------
__global__ __launch_bounds__(256) void k0b_transpose(
    const float* __restrict__ Wq, const float* __restrict__ Wk,
    const float* __restrict__ Wv, const float* __restrict__ Wsk,
    const float* __restrict__ We, bf16* __restrict__ wT)
{
    int tid = blockIdx.x * 256 + threadIdx.x;
    if (tid >= 5 * 128 * 128) return;
    int mat = tid >> 14;
    int n = (tid >> 7) & 127;
    int k = tid & 127;
    const float* W = (mat == 0) ? Wq : (mat == 1) ? Wk : (mat == 2) ? Wv : (mat == 3) ? Wsk : We;
    wT[tid] = f2b(W[k * 128 + n]);
}

// ---------------------------------------------------------------------------
// K1: persistent node projections via MFMA. 512 blocks; g = blockIdx&3 picks
// {Wq,Wk,Wv,Wskip}; weight staged in LDS ONCE. 128-node tiles; U rows are
// wave-private (wave w owns rows 16w..16w+16) -> no barriers in the loop.
// ---------------------------------------------------------------------------
__global__ __launch_bounds__(512) void k1_node_proj(
    const float* __restrict__ x, const bf16* __restrict__ wT,
    const float* __restrict__ bq, const float* __restrict__ bk,
    const float* __restrict__ bv, const float* __restrict__ bsk,
    bf16* __restrict__ qn, bf16* __restrict__ kn, bf16* __restrict__ vn,
    float* __restrict__ out_acc)
{
    __shared__ __align__(16) bf16 wts[HC * LDK];   // 34.8 KB
    __shared__ __align__(16) bf16 U[MPT * LDK];    // 34.8 KB (x-tile, then out-tile)

    int tid = threadIdx.x;
    int lane = tid & 63, wave = tid >> 6;
    int g = blockIdx.x & 3;
    int group = blockIdx.x >> 2;            // 0..127
    int m0 = wave * 16, r = lane & 15, quad = lane >> 4;

    const bf16* WgT = wT + (size_t)g * 128 * 128;
    for (int idx = tid; idx < HC * (EDD / 8); idx += 512) {
        int n = idx >> 4, seg = idx & 15;
        *reinterpret_cast<uint4*>(&wts[n * LDK + seg * 8]) =
            *reinterpret_cast<const uint4*>(WgT + n * 128 + seg * 8);
    }
    const float* B = (g == 0) ? bq : (g == 1) ? bk : (g == 2) ? bv : bsk;
    float bias_r[8];
    #pragma unroll
    for (int nt = 0; nt < 8; ++nt) bias_r[nt] = B[nt * 16 + r];
    __syncthreads();   // wts ready; the ONLY barrier

    bf16* Og = (g == 0) ? qn : (g == 1) ? kn : vn;  // unused when g==3
    const int nTiles = (NN + MPT - 1) / MPT;        // 782

    for (int tile = group; tile < nTiles; tile += 128) {
        int row_base = tile * MPT + m0;
        if (row_base >= NN) continue;   // wave-uniform

        // stage own 16 rows of x as bf16
        for (int m = 0; m < 16; ++m) {
            int node = row_base + m; if (node >= NN) node = NN - 1;
            float2 xv = *reinterpret_cast<const float2*>(x + (size_t)node * INC + 2 * lane);
            __hip_bfloat162 h; h.x = f2b(xv.x); h.y = f2b(xv.y);
            *reinterpret_cast<__hip_bfloat162*>(&U[(m0 + m) * LDK + 2 * lane]) = h;
        }

        floatx4 acc[8];
        #pragma unroll
        for (int i = 0; i < 8; ++i) acc[i] = (floatx4){0.f, 0.f, 0.f, 0.f};
        #pragma unroll
        for (int k0 = 0; k0 < 128; k0 += 32) {
            short8 a = *reinterpret_cast<const short8*>(&U[(m0 + r) * LDK + k0 + quad * 8]);
            #pragma unroll
            for (int nt = 0; nt < 8; ++nt) {
                short8 b = *reinterpret_cast<const short8*>(&wts[(nt * 16 + r) * LDK + k0 + quad * 8]);
                acc[nt] = __builtin_amdgcn_mfma_f32_16x16x32_bf16(a, b, acc[nt], 0, 0, 0);
            }
        }

        if (g < 3) {
            // out tile -> U own rows (bf16, +bias), then coalesced copy out
            #pragma unroll
            for (int nt = 0; nt < 8; ++nt) {
                int col = nt * 16 + r;
                #pragma unroll
                for (int rg = 0; rg < 4; ++rg)
                    U[(m0 + quad * 4 + rg) * LDK + col] = f2b(acc[nt][rg] + bias_r[nt]);
            }
            #pragma unroll
            for (int p = 0; p < 4; ++p) {
                int row = m0 + p * 4 + quad;
                int node = tile * MPT + row;
                if (node < NN)
                    *reinterpret_cast<uint4*>(Og + (size_t)node * HC + r * 8) =
                        *reinterpret_cast<const uint4*>(&U[row * LDK + r * 8]);
            }
        } else {
            #pragma unroll
            for (int nt = 0; nt < 8; ++nt) {
                int col = nt * 16 + r;
                #pragma unroll
                for (int rg = 0; rg < 4; ++rg) {
                    int node = tile * MPT + m0 + quad * 4 + rg;
                    if (node < NN) out_acc[(size_t)node * HC + col] = acc[nt][rg] + bias_r[nt];
                }
            }
        }
    }
}

// ---------------------------------------------------------------------------
// K2: persistent edge pass via MFMA. 512 blocks x 512 threads; We staged ONCE.
// 128-edge tiles; U rows wave-private: build edge_attr -> MFMA -> e back into
// U -> coalesced e_ws store -> alpha epilogue. Zero barriers in steady loop.
// ---------------------------------------------------------------------------
__global__ __launch_bounds__(512) void k2_edge_alpha(
    const int* __restrict__ eidx,
    const float* __restrict__ lu, const float* __restrict__ t, const float* __restrict__ msg,
    const float* __restrict__ wtv, const float* __restrict__ btv,
    const bf16* __restrict__ WeT,
    const bf16* __restrict__ qn, const bf16* __restrict__ kn,
    bf16* __restrict__ e_ws, float* __restrict__ alpha, int* __restrict__ amax)
{
    __shared__ __align__(16) bf16 wts[HC * LDK];   // 34.8 KB
    __shared__ __align__(16) bf16 U[MPT * LDK];    // 34.8 KB (edge_attr, then e)

    int tid = threadIdx.x;
    int lane = tid & 63, wave = tid >> 6;
    int m0 = wave * 16, r = lane & 15, quad = lane >> 4;

    for (int idx = tid; idx < HC * (EDD / 8); idx += 512) {
        int n = idx >> 4, seg = idx & 15;
        *reinterpret_cast<uint4*>(&wts[n * LDK + seg * 8]) =
            *reinterpret_cast<const uint4*>(WeT + n * 128 + seg * 8);
    }
    float wt_r = wtv[lane];   // lane's time-enc weight (TDIM==64)
    float bt_r = btv[lane];
    __syncthreads();   // the ONLY barrier

    const int nTiles = (NE + MPT - 1) / MPT;   // 4688

    for (int tile = blockIdx.x; tile < nTiles; tile += gridDim.x) {
        int e_base = tile * MPT + m0;
        int rem = NE - e_base;
        if (rem <= 0) continue;    // wave-uniform
        int nvalid = rem < 16 ? rem : 16;

        // lane<16 holds meta for edge e_base+lane
        int srcn = 0, dstn = 0; float relv = 0.f;
        if (lane < 16) {
            int ce = e_base + lane; if (ce >= NE) ce = NE - 1;
            srcn = eidx[ce];
            dstn = eidx[NE + ce];
            relv = lu[srcn] - t[ce];
        }

        // build own 16 rows of edge_attr: col lane -> cos, col 64+lane -> msg
        for (int m = 0; m < 16; ++m) {
            int em = e_base + m; if (em >= NE) em = NE - 1;
            float rel_m = __shfl(relv, m);
            U[(m0 + m) * LDK + lane]      = f2b(cosf(fmaf(rel_m, wt_r, bt_r)));
            U[(m0 + m) * LDK + 64 + lane] = f2b(msg[(size_t)em * MSGD + lane]);
        }

        floatx4 acc[8];
        #pragma unroll
        for (int i = 0; i < 8; ++i) acc[i] = (floatx4){0.f, 0.f, 0.f, 0.f};
        #pragma unroll
        for (int k0 = 0; k0 < 128; k0 += 32) {
            short8 a = *reinterpret_cast<const short8*>(&U[(m0 + r) * LDK + k0 + quad * 8]);
            #pragma unroll
            for (int nt = 0; nt < 8; ++nt) {
                short8 b = *reinterpret_cast<const short8*>(&wts[(nt * 16 + r) * LDK + k0 + quad * 8]);
                acc[nt] = __builtin_amdgcn_mfma_f32_16x16x32_bf16(a, b, acc[nt], 0, 0, 0);
            }
        }

        // e tile -> U own rows (data-dep ordered after the A-frag reads)
        #pragma unroll
        for (int nt = 0; nt < 8; ++nt) {
            int col = nt * 16 + r;
            #pragma unroll
            for (int rg = 0; rg < 4; ++rg)
                U[(m0 + quad * 4 + rg) * LDK + col] = f2b(acc[nt][rg]);
        }

        // coalesced e_ws store (own rows)
        #pragma unroll
        for (int p = 0; p < 4; ++p) {
            int row = m0 + p * 4 + quad;
            int ee = tile * MPT + row;
            if (ee < NE)
                *reinterpret_cast<uint4*>(e_ws + (size_t)ee * HC + r * 8) =
                    *reinterpret_cast<const uint4*>(&U[row * LDK + r * 8]);
        }

        // alpha epilogue (own rows)
        for (int m = 0; m < nvalid; ++m) {
            int sm = __shfl(srcn, m), dm = __shfl(dstn, m);
            float2 qv = bload2(&qn[(size_t)dm * HC + 2 * lane]);
            float2 kv = bload2(&kn[(size_t)sm * HC + 2 * lane]);
            float2 ev = bload2(&U[(m0 + m) * LDK + 2 * lane]);
            float part = qv.x * (kv.x + ev.x) + qv.y * (kv.y + ev.y);
            part += __shfl_xor(part, 1);
            part += __shfl_xor(part, 2);
            part += __shfl_xor(part, 4);
            part += __shfl_xor(part, 8);
            part += __shfl_xor(part, 16);
            if ((lane & 31) == 0) {
                int h = lane >> 5;
                float a = part * 0.125f;   // 1/sqrt(64)
                alpha[(size_t)(e_base + m) * NH + h] = a;
                atomicMax(&amax[dm * NH + h], f2ord(a));
            }
        }
    }
}

// ---------------------------------------------------------------------------
// K3: ex = exp(alpha - amax[dst]); alpha <- ex; denom[dst] += ex
// ---------------------------------------------------------------------------
__global__ __launch_bounds__(256) void k3_softmax(
    const int* __restrict__ eidx, const int* __restrict__ amax,
    float* __restrict__ alpha, float* __restrict__ denom)
{
    int tid = blockIdx.x * 256 + threadIdx.x;
    if (tid >= NE * NH) return;
    int e = tid >> 1, h = tid & 1;
    int dstn = eidx[NE + e];
    float m = ord2f(amax[dstn * NH + h]);
    if (!(m > -1e29f && m < 1e29f)) m = 0.0f;   // mirrors reference isfinite()
    float ex = expf(alpha[tid] - m);
    alpha[tid] = ex;
    atomicAdd(&denom[dstn * NH + h], ex);
}

// ---------------------------------------------------------------------------
// K4: out_acc[dst,c] += attn * (v[src,c] + e[edge,c]); 4 channels per thread
// ---------------------------------------------------------------------------
__global__ __launch_bounds__(256) void k4_agg(
    const int* __restrict__ eidx, const float* __restrict__ alpha,
    const float* __restrict__ denom, const bf16* __restrict__ vn,
    const bf16* __restrict__ e_ws, float* __restrict__ out_acc)
{
    int tid = blockIdx.x * 256 + threadIdx.x;
    if (tid >= NE * 32) return;
    int e = tid >> 5, qq = tid & 31;
    int c0 = qq * 4, h = c0 >> 6;
    int dstn = eidx[NE + e];
    int srcn = eidx[e];
    float ex  = alpha[e * NH + h];
    float den = denom[dstn * NH + h];
    float attn = ex / (den + 1e-16f);
    float2 ev01 = bload2(e_ws + (size_t)e * HC + c0);
    float2 ev23 = bload2(e_ws + (size_t)e * HC + c0 + 2);
    float2 vv01 = bload2(vn + (size_t)srcn * HC + c0);
    float2 vv23 = bload2(vn + (size_t)srcn * HC + c0 + 2);
    float* dst = out_acc + (size_t)dstn * HC + c0;
    atomicAdd(dst + 0, attn * (vv01.x + ev01.x));
    atomicAdd(dst + 1, attn * (vv01.y + ev01.y));
    atomicAdd(dst + 2, attn * (vv23.x + ev23.x));
    atomicAdd(dst + 3, attn * (vv23.y + ev23.y));
}

// ---------------------------------------------------------------------------
// K5: f32 accumulator -> f32 output
// ---------------------------------------------------------------------------
__global__ __launch_bounds__(256) void k5_final(
    const float* __restrict__ out_acc, float* __restrict__ out)
{
    int tid = blockIdx.x * 256 + threadIdx.x;
    if (tid < NN * HC) out[tid] = out_acc[tid];
}

// ---------------------------------------------------------------------------
extern "C" void kernel_launch(void* const* d_in, const int* in_sizes, int n_in,
                              void* d_out, int out_size, void* d_ws, size_t ws_size,
                              hipStream_t stream)
{
    const float* x   = (const float*)d_in[0];
    const float* lu  = (const float*)d_in[1];
    const int*   eidx= (const int*)d_in[2];
    const float* t   = (const float*)d_in[3];
    const float* msg = (const float*)d_in[4];
    const float* wt  = (const float*)d_in[5];
    const float* bt  = (const float*)d_in[6];
    const float* Wq  = (const float*)d_in[7];
    const float* bq  = (const float*)d_in[8];
    const float* Wk  = (const float*)d_in[9];
    const float* bk  = (const float*)d_in[10];
    const float* Wv  = (const float*)d_in[11];
    const float* bv  = (const float*)d_in[12];
    const float* We  = (const float*)d_in[13];
    const float* Wsk = (const float*)d_in[14];
    const float* bsk = (const float*)d_in[15];
    float* out = (float*)d_out;

    // workspace layout
    char* ws = (char*)d_ws;
    size_t off = 0;
    bf16*  qn      = (bf16*)(ws + off);  off += (size_t)NN * HC * 2;   // 25.6 MB
    bf16*  kn      = (bf16*)(ws + off);  off += (size_t)NN * HC * 2;   // 25.6 MB
    bf16*  vn      = (bf16*)(ws + off);  off += (size_t)NN * HC * 2;   // 25.6 MB
    float* out_acc = (float*)(ws + off); off += (size_t)NN * HC * 4;   // 51.2 MB
    float* alpha   = (float*)(ws + off); off += (size_t)NE * NH * 4;   // 4.8 MB
    int*   amax    = (int*)(ws + off);   off += (size_t)NN * NH * 4;   // 0.8 MB
    float* denom   = (float*)(ws + off); off += (size_t)NN * NH * 4;   // 0.8 MB
    bf16*  e_ws    = (bf16*)(ws + off);  off += (size_t)NE * HC * 2;   // 153.6 MB
    bf16*  wT      = (bf16*)(ws + off);  off += (size_t)5 * 128 * 128 * 2;

    k0_init<<<(NN * NH + 255) / 256, 256, 0, stream>>>(amax, denom);

    k0b_transpose<<<(5 * 128 * 128) / 256, 256, 0, stream>>>(Wq, Wk, Wv, Wsk, We, wT);

    k1_node_proj<<<512, 512, 0, stream>>>(
        x, wT, bq, bk, bv, bsk, qn, kn, vn, out_acc);

    k2_edge_alpha<<<512, 512, 0, stream>>>(
        eidx, lu, t, msg, wt, bt, wT + (size_t)4 * 128 * 128,
        qn, kn, e_ws, alpha, amax);

    k3_softmax<<<(NE * NH + 255) / 256, 256, 0, stream>>>(eidx, amax, alpha, denom);

    k4_agg<<<(NE * 32 + 255) / 256, 256, 0, stream>>>(eidx, alpha, denom, vn, e_ws, out_acc);

    k5_final<<<(NN * HC + 255) / 256, 256, 0, stream>>>(out_acc, out);
}